// Round 5
// baseline (393.060 us; speedup 1.0000x reference)
//
#include <hip/hip_runtime.h>
#include <hip/hip_bf16.h>

// Problem constants (fixed by setup_inputs)
#define T_SZ 32
#define B_SZ 512
#define F_SZ 2048
#define H_SZ 2048
#define M_SZ (T_SZ * B_SZ)   // 16384 GEMM rows

// GEMM: faithful m201-style 8-phase schedule, ported to MX-fp8 32x32x64.
// BM=BN=256, BK=128 (2 k-steps of 64), 512 threads = 8 waves (2M x 4N),
// wave tile 128x64 = 4x2 acc frags (128 AGPR). 128 KB static LDS:
// 2 buffers x [Ak0|Ak1|Bk0|Bk1] 16KB subtiles (64-B rows, u^((row>>1)&3) swizzle --
// R4-verified low-conflict involution). Per phase: {ds_read own frags; 1 gload/thread
// stage; barrier; lgkmcnt(0); setprio(1); 2 MFMA; setprio(0); barrier}.
// Counted vmcnt(4) ONLY before the trailing barriers of phases 3 and 7.
#define BM 256
#define BN 256
#define BK 128
#define NT (F_SZ / BK)        // 16 K-tile iterations
#define SUB_BYTES 16384       // one K-half subtile: 256 rows x 64 B
#define BUF_BYTES 65536       // Ak0+Ak1+Bk0+Bk1

typedef int   i32x8  __attribute__((ext_vector_type(8)));    // 32 fp8 = 8 VGPRs (MFMA A/B frag)
typedef float f32x16 __attribute__((ext_vector_type(16)));   // 32x32 MFMA C/D frag

__device__ __forceinline__ void gload_lds16(const void* g, void* l) {
    // async global->LDS, 16 B/lane. LDS dest is wave-uniform base + lane*16 (linear);
    // the bank swizzle is implemented by permuting the per-lane GLOBAL source address.
    __builtin_amdgcn_global_load_lds(
        (const __attribute__((address_space(1))) unsigned int*)g,
        (__attribute__((address_space(3))) unsigned int*)l,
        16, 0, 0);
}

__device__ __forceinline__ float bf16_bits_to_f32(unsigned short u) {
    return __uint_as_float(((unsigned)u) << 16);
}

__device__ __forceinline__ void sbar() {
    __builtin_amdgcn_sched_barrier(0);
    __builtin_amdgcn_s_barrier();
    __builtin_amdgcn_sched_barrier(0);
}

#define LGKM0 do { asm volatile("s_waitcnt lgkmcnt(0)" ::: "memory"); \
                   __builtin_amdgcn_sched_barrier(0); } while (0)
#define VMW(n) asm volatile("s_waitcnt vmcnt(" #n ")" ::: "memory")

#define MFMA_FP8(a, b, c) __builtin_amdgcn_mfma_scale_f32_32x32x64_f8f6f4( \
        (a), (b), (c), 0 /*A e4m3*/, 0 /*B e4m3*/, 0, 0x7f7f7f7f, 0, 0x7f7f7f7f)

// ---------------- fp32 -> fp8 e4m3 (OCP), 8 elems/thread, optional pre-scale ----------------
__global__ __launch_bounds__(256) void cvt_fp8_kernel(const float* __restrict__ in,
                                                      unsigned int* __restrict__ out,
                                                      float scale, int n8) {
    int i = blockIdx.x * 256 + threadIdx.x;
    if (i >= n8) return;
    float4 v0 = ((const float4*)in)[2 * i];
    float4 v1 = ((const float4*)in)[2 * i + 1];
    int w0 = __builtin_amdgcn_cvt_pk_fp8_f32(v0.x * scale, v0.y * scale, 0, false);
    w0     = __builtin_amdgcn_cvt_pk_fp8_f32(v0.z * scale, v0.w * scale, w0, true);
    int w1 = __builtin_amdgcn_cvt_pk_fp8_f32(v1.x * scale, v1.y * scale, 0, false);
    w1     = __builtin_amdgcn_cvt_pk_fp8_f32(v1.z * scale, v1.w * scale, w1, true);
    ((uint2*)out)[i] = make_uint2((unsigned)w0, (unsigned)w1);
}

// ---------------- zero the row sum-of-squares accumulator (ws is poisoned 0xAA) ----------------
__global__ __launch_bounds__(256) void init_ss_kernel(float4* __restrict__ ss4) {
    ss4[blockIdx.x * 256 + threadIdx.x] = make_float4(0.f, 0.f, 0.f, 0.f);
}

// ---------------- GEMM (MX-fp8) + fused row-SS, 8-phase m201 schedule ----------------
// C[m,n] = (1/256) * sum_k A8[m,k]*B8[n,k] + bias[n];  ss[m] += sum_n C[m,n]^2 (atomic)
//
// Iteration kt reads buf[kt&1], stages tile kt+1 into buf[(kt+1)&1], 1 gload/thread/phase:
//   ph0:Ak0.p0  ph1:Bk0.p0  ph2:Ak0.p1  ph3:Bk0.p1  ph4:Ak1.p0  ph5:Bk1.p0  ph6:Ak1.p1  ph7:Bk1.p1
// vmcnt FIFO induction (8 loads/iter): end-of-iter vmcnt(4) drains tile kt+1's {Ak0,Bk0}
// (leaves its {Ak1,Bk1} + nothing else); phase-3 vmcnt(4) drains tile kt's {Ak1,Bk1}
// (4 older) while this iter's 4 new loads stay in flight. Tail: kt==NT-1 phase-3 uses
// vmcnt(0); kt==NT-1 end skips. Prologue stages tile 0 fully + vmcnt(0) + barrier.
// Slot overwrite safety: buf[(kt+1)&1] last ds_read in iter kt-1, whose reads complete
// at its phase-7 LGKM0 before the end-of-iter barrier; iter kt's stages issue after it.
__global__ __launch_bounds__(512, 2) void gemm_fp8_kernel(const unsigned char* __restrict__ A,   // [M_SZ,F_SZ] fp8
                                                          const unsigned char* __restrict__ Bt,  // [H_SZ,F_SZ] fp8 (x256)
                                                          const float* __restrict__ bias,        // [H_SZ]
                                                          __hip_bfloat16* __restrict__ C,        // [M_SZ,H_SZ] bf16
                                                          float* __restrict__ ss)                // [M_SZ] atomic SS
{
    __shared__ __align__(16) unsigned char smem[2 * BUF_BYTES];  // 128 KB static

    const int tid  = threadIdx.x;
    const int lane = tid & 63;
    const int wave = tid >> 6;           // 0..7
    const int wm   = wave >> 2;          // 0..1 -> 128-row half
    const int wn   = wave & 3;           // 0..3 -> 64-col quarter
    const int l31  = lane & 31;
    const int kh   = lane >> 5;          // k-half within a 64B MFMA slice

    // bijective XCD-chunk swizzle: 512 blocks, XCD k (= flat%8) gets logical ids
    // [k*64, (k+1)*64) = 8 m-panels x all 8 n-panels -> L2-resident reuse.
    const int flat = blockIdx.y * 8 + blockIdx.x;
    const int swz  = (flat & 7) * 64 + (flat >> 3);
    const int n0   = (swz & 7) * BN;
    const int m0   = (swz >> 3) * BM;

    const unsigned char* const Ap = A  + (size_t)m0 * F_SZ;
    const unsigned char* const Bp = Bt + (size_t)n0 * F_SZ;

    // staging offsets: subtile = [256 rows][4 units of 16B], swizzle u_log = (idx&3)^((row>>1)&3)
    // idx = pr*512 + tid; LDS dest linear (idx*16), source permuted.
    int gOff[2], lOff[2];
    #pragma unroll
    for (int pr = 0; pr < 2; ++pr) {
        const int idx = pr * 512 + tid;
        const int row = idx >> 2;
        const int u   = (idx & 3) ^ ((row >> 1) & 3);
        gOff[pr] = row * F_SZ + u * 16;
        lOff[pr] = idx * 16;
    }

    // fragment read offsets within a subtile (add ks*SUB_BYTES at use)
    int aoffb[4][2], boffb[2][2];
    #pragma unroll
    for (int mi = 0; mi < 4; ++mi) {
        const int ra = wm * 128 + mi * 32 + l31;
        #pragma unroll
        for (int j = 0; j < 2; ++j)
            aoffb[mi][j] = ra * 64 + (((kh * 2 + j) ^ ((ra >> 1) & 3)) * 16);
    }
    #pragma unroll
    for (int ni = 0; ni < 2; ++ni) {
        const int rb = wn * 64 + ni * 32 + l31;
        #pragma unroll
        for (int j = 0; j < 2; ++j)
            boffb[ni][j] = rb * 64 + (((kh * 2 + j) ^ ((rb >> 1) & 3)) * 16);
    }

    f32x16 acc[4][2] = {};
    i32x8 bq[2];

    // prologue: tile 0 fully staged into buf0
    {
        unsigned char* const d = smem;
        #pragma unroll
        for (int ks = 0; ks < 2; ++ks)
            #pragma unroll
            for (int pr = 0; pr < 2; ++pr) {
                gload_lds16(Ap + ks * 64 + gOff[pr], d + ks * SUB_BYTES + lOff[pr]);
                gload_lds16(Bp + ks * 64 + gOff[pr], d + 2 * SUB_BYTES + ks * SUB_BYTES + lOff[pr]);
            }
        VMW(0);
        sbar();
    }

    #pragma unroll 1
    for (int kt = 0; kt < NT; ++kt) {
        const unsigned char* const buf = smem + (kt & 1) * BUF_BYTES;
        unsigned char* const nb        = smem + ((kt + 1) & 1) * BUF_BYTES;
        const bool stg = (kt + 1 < NT);
        const int  kb  = (kt + 1) * BK;

// STG_A/STG_B: stage one 512-chunk part of a K-half subtile of tile kt+1
#define STG_A(ks, pr) do { if (stg) gload_lds16(Ap + kb + (ks) * 64 + gOff[pr], \
                                                nb + (ks) * SUB_BYTES + lOff[pr]); } while (0)
#define STG_B(ks, pr) do { if (stg) gload_lds16(Bp + kb + (ks) * 64 + gOff[pr], \
                                                nb + 2 * SUB_BYTES + (ks) * SUB_BYTES + lOff[pr]); } while (0)

#define PHASE(ks, mi, STAGE_STMT, PRE_TRAIL) do {                              \
        i32x8 aw;                                                              \
        if ((mi) == 0) {                                                       \
            const unsigned char* Bb = buf + 2 * SUB_BYTES + (ks) * SUB_BYTES;  \
            ((int4*)&bq[0])[0] = *(const int4*)(Bb + boffb[0][0]);             \
            ((int4*)&bq[0])[1] = *(const int4*)(Bb + boffb[0][1]);             \
            ((int4*)&bq[1])[0] = *(const int4*)(Bb + boffb[1][0]);             \
            ((int4*)&bq[1])[1] = *(const int4*)(Bb + boffb[1][1]);             \
        }                                                                      \
        {                                                                      \
            const unsigned char* Ab = buf + (ks) * SUB_BYTES;                  \
            ((int4*)&aw)[0] = *(const int4*)(Ab + aoffb[mi][0]);               \
            ((int4*)&aw)[1] = *(const int4*)(Ab + aoffb[mi][1]);               \
        }                                                                      \
        STAGE_STMT;                                                            \
        sbar();                    /* leading barrier absorbs ds latency */    \
        LGKM0;                                                                 \
        __builtin_amdgcn_s_setprio(1);                                         \
        acc[mi][0] = MFMA_FP8(aw, bq[0], acc[mi][0]);                          \
        acc[mi][1] = MFMA_FP8(aw, bq[1], acc[mi][1]);                          \
        __builtin_amdgcn_s_setprio(0);                                         \
        PRE_TRAIL;                                                             \
        sbar();                    /* trailing barrier */                      \
    } while (0)

        PHASE(0, 0, STG_A(0, 0), );
        PHASE(0, 1, STG_B(0, 0), );
        PHASE(0, 2, STG_A(0, 1), );
        PHASE(0, 3, STG_B(0, 1), { if (kt != NT - 1) { VMW(4); } else { VMW(0); } });
        PHASE(1, 0, STG_A(1, 0), );
        PHASE(1, 1, STG_B(1, 0), );
        PHASE(1, 2, STG_A(1, 1), );
        PHASE(1, 3, STG_B(1, 1), { if (kt < NT - 1) { VMW(4); } });

#undef PHASE
#undef STG_A
#undef STG_B
    }

    // epilogue: 32x32 C/D layout col=lane&31, row=(r&3)+8*(r>>2)+4*(lane>>5)  (m74/m101-verified)
    float bv[2];
    #pragma unroll
    for (int ni = 0; ni < 2; ++ni) bv[ni] = bias[n0 + wn * 64 + ni * 32 + l31];
    #pragma unroll
    for (int mi = 0; mi < 4; ++mi) {
        const int gmb = m0 + wm * 128 + mi * 32 + 4 * kh;
        #pragma unroll
        for (int r = 0; r < 16; ++r) {
            const int grow = gmb + (r & 3) + 8 * (r >> 2);
            float p = 0.f;
            #pragma unroll
            for (int ni = 0; ni < 2; ++ni) {
                const int gn = n0 + wn * 64 + ni * 32 + l31;
                const float val = acc[mi][ni][r] * (1.0f / 256.0f) + bv[ni];
                C[(size_t)grow * H_SZ + gn] = __float2bfloat16(val);
                p += val * val;
            }
            // cross-lane: sum over the 32 col-lanes (masks<32 stay in-half)
            p += __shfl_xor(p, 1, 64);
            p += __shfl_xor(p, 2, 64);
            p += __shfl_xor(p, 4, 64);
            p += __shfl_xor(p, 8, 64);
            p += __shfl_xor(p, 16, 64);
            if (l31 == 0) atomicAdd(ss + grow, p);
        }
    }
}

// ---------------- LIF scan: 4 columns/thread, inv-norm in LDS, 3-deep load pipeline ----------------
__global__ __launch_bounds__(256) void lif_scan_kernel(const __hip_bfloat16* __restrict__ cur, // [M_SZ,H_SZ]
                                                       const float* __restrict__ ss,           // [M_SZ] sum-of-squares
                                                       float* __restrict__ spk,                // [T,B,H]
                                                       float* __restrict__ cnt)                // [B,H]
{
    __shared__ float s_inv[T_SZ];
    const int gid = blockIdx.x * 256 + threadIdx.x;     // 262144 threads
    const int b   = gid >> 9;                           // uniform within a block
    const int h0  = (gid & 511) * 4;

    if (threadIdx.x < T_SZ)
        s_inv[threadIdx.x] = 1.0f / fmaxf(sqrtf(ss[threadIdx.x * B_SZ + b]), 1e-12f);
    __syncthreads();

    const size_t stride = (size_t)B_SZ * H_SZ;
    const size_t base   = (size_t)b * H_SZ + h0;
    const __hip_bfloat16* p = cur + base;

    ushort4 pk[3];
    pk[0] = *(const ushort4*)(p);
    pk[1] = *(const ushort4*)(p + stride);
    pk[2] = *(const ushort4*)(p + 2 * stride);

    float v[4]  = {0, 0, 0, 0};
    float cn[4] = {0, 0, 0, 0};
    #pragma unroll
    for (int t = 0; t < T_SZ; ++t) {
        const ushort4 k = pk[t % 3];
        if (t + 3 < T_SZ) pk[t % 3] = *(const ushort4*)(p + (size_t)(t + 3) * stride);
        const float inv = s_inv[t];
        float so[4];
        {
            float c;
            c = bf16_bits_to_f32(k.x) * inv; v[0] += (c - v[0]) * 0.5f;
            c = bf16_bits_to_f32(k.y) * inv; v[1] += (c - v[1]) * 0.5f;
            c = bf16_bits_to_f32(k.z) * inv; v[2] += (c - v[2]) * 0.5f;
            c = bf16_bits_to_f32(k.w) * inv; v[3] += (c - v[3]) * 0.5f;
        }
        #pragma unroll
        for (int j = 0; j < 4; ++j) {
            float s = (v[j] >= 1.0f) ? 1.0f : 0.0f;
            so[j] = s;
            cn[j] += s;
            v[j] = (s != 0.f) ? 0.f : v[j];
        }
        *(float4*)(spk + base + (size_t)t * stride) = make_float4(so[0], so[1], so[2], so[3]);
    }
    *(float4*)(cnt + base) = make_float4(cn[0], cn[1], cn[2], cn[3]);
}

extern "C" void kernel_launch(void* const* d_in, const int* in_sizes, int n_in,
                              void* d_out, int out_size, void* d_ws, size_t ws_size,
                              hipStream_t stream) {
    const float* x    = (const float*)d_in[0];   // [T,B,F] fp32
    const float* W    = (const float*)d_in[1];   // [H,F]  fp32
    const float* bias = (const float*)d_in[2];   // [H]    fp32

    float* spk = (float*)d_out;                          // [T,B,H]
    float* cnt = spk + (size_t)T_SZ * B_SZ * H_SZ;       // [B,H]

    char* ws = (char*)d_ws;
    unsigned char* x8    = (unsigned char*)ws;                                   // 33.5 MB
    unsigned char* W8    = x8 + (size_t)M_SZ * F_SZ;                             // 4.2 MB
    __hip_bfloat16* curb = (__hip_bfloat16*)(W8 + (size_t)H_SZ * F_SZ);          // 67.1 MB
    float* ss            = (float*)((char*)curb + (size_t)M_SZ * H_SZ * 2);      // 64 KB

    init_ss_kernel<<<M_SZ / 1024, 256, 0, stream>>>((float4*)ss);
    cvt_fp8_kernel<<<(M_SZ * F_SZ / 8) / 256, 256, 0, stream>>>(x, (unsigned int*)x8, 1.0f,   M_SZ * F_SZ / 8);
    cvt_fp8_kernel<<<(H_SZ * F_SZ / 8) / 256, 256, 0, stream>>>(W, (unsigned int*)W8, 256.0f, H_SZ * F_SZ / 8);
    gemm_fp8_kernel<<<dim3(H_SZ / BN, M_SZ / BM), 512, 0, stream>>>(x8, W8, bias, curb, ss);
    lif_scan_kernel<<<(B_SZ * H_SZ / 4) / 256, 256, 0, stream>>>(curb, ss, spk, cnt);
}

// Round 8
// 357.322 us; speedup vs baseline: 1.1000x; 1.1000x over previous
//
#include <hip/hip_runtime.h>
#include <hip/hip_bf16.h>

// Problem constants (fixed by setup_inputs)
#define T_SZ 32
#define B_SZ 512
#define F_SZ 2048
#define H_SZ 2048
#define M_SZ (T_SZ * B_SZ)   // 16384 GEMM rows

// GEMM tile: BM=256, BN=128, BK=64. 4 waves (2M x 2N), wave tile 128x64 = 4x2 MFMA frags.
// R4 structure (best measured: 364us total, gemm 110us, MfmaUtil 26%): TRIPLE-buffered
// LDS (72 KB/block, 2 blocks/CU), tile kt+2 staged during kt, ONE barrier per kt,
// counted vmcnt(6), swizzle u ^ ((row>>1)&3) (R4-verified: conflicts 18.9M -> 6.3M).
// This round: byte-identical GEMM + lif_scan to the R4-passing build; ONLY change is
// the fused prep kernel (init_ss + cvt_x + cvt_W in one launch, 5 -> 3 launches).
#define BM 256
#define BN 128
#define BK 64
#define NT (F_SZ / BK)            // 32 K-tiles
#define ABYTES (BM * BK)          // 16 KB
#define BBYTES (BN * BK)          // 8 KB
#define TILE_BYTES (ABYTES + BBYTES)  // 24 KB per buffer

typedef int   i32x8  __attribute__((ext_vector_type(8)));    // 32 fp8 = 8 VGPRs (MFMA A/B frag)
typedef float f32x16 __attribute__((ext_vector_type(16)));   // 32x32 MFMA C/D frag

__device__ __forceinline__ void gload_lds16(const void* g, void* l) {
    // async global->LDS, 16 B/lane. LDS dest is wave-uniform base + lane*16 (linear);
    // the bank swizzle is implemented by permuting the per-lane GLOBAL source address.
    __builtin_amdgcn_global_load_lds(
        (const __attribute__((address_space(1))) unsigned int*)g,
        (__attribute__((address_space(3))) unsigned int*)l,
        16, 0, 0);
}

__device__ __forceinline__ float bf16_bits_to_f32(unsigned short u) {
    return __uint_as_float(((unsigned)u) << 16);
}

__device__ __forceinline__ void sbar() {
    __builtin_amdgcn_sched_barrier(0);
    __builtin_amdgcn_s_barrier();
    __builtin_amdgcn_sched_barrier(0);
}

#define MFMA_FP8(a, b, c) __builtin_amdgcn_mfma_scale_f32_32x32x64_f8f6f4( \
        (a), (b), (c), 0 /*A e4m3*/, 0 /*B e4m3*/, 0, 0x7f7f7f7f, 0, 0x7f7f7f7f)

// ---------------- fused prep: fp32->fp8 for x (scale 1) and W (scale 256) + ss zero ----
// One launch replaces init_ss + 2x cvt_fp8 (3 launches serialized on the stream).
#define NBLK_X ((M_SZ * F_SZ / 8) / 256)   // 16384
#define NBLK_W ((H_SZ * F_SZ / 8) / 256)   // 2048
#define NBLK_S ((M_SZ / 4) / 256)          // 16

__device__ __forceinline__ void cvt8(const float* __restrict__ in,
                                     unsigned int* __restrict__ out,
                                     float scale, int i) {
    float4 v0 = ((const float4*)in)[2 * i];
    float4 v1 = ((const float4*)in)[2 * i + 1];
    int w0 = __builtin_amdgcn_cvt_pk_fp8_f32(v0.x * scale, v0.y * scale, 0, false);
    w0     = __builtin_amdgcn_cvt_pk_fp8_f32(v0.z * scale, v0.w * scale, w0, true);
    int w1 = __builtin_amdgcn_cvt_pk_fp8_f32(v1.x * scale, v1.y * scale, 0, false);
    w1     = __builtin_amdgcn_cvt_pk_fp8_f32(v1.z * scale, v1.w * scale, w1, true);
    ((uint2*)out)[i] = make_uint2((unsigned)w0, (unsigned)w1);
}

__global__ __launch_bounds__(256) void prep_kernel(const float* __restrict__ x,
                                                   const float* __restrict__ W,
                                                   unsigned int* __restrict__ x8,
                                                   unsigned int* __restrict__ W8,
                                                   float4* __restrict__ ss4) {
    const int bid = blockIdx.x;
    if (bid < NBLK_X) {
        cvt8(x, x8, 1.0f, bid * 256 + threadIdx.x);
    } else if (bid < NBLK_X + NBLK_W) {
        cvt8(W, W8, 256.0f, (bid - NBLK_X) * 256 + threadIdx.x);
    } else {
        ss4[(bid - NBLK_X - NBLK_W) * 256 + threadIdx.x] = make_float4(0.f, 0.f, 0.f, 0.f);
    }
}

// ---------------- GEMM (MX-fp8) + fused row-SS ----------------
// C[m,n] = (1/256) * sum_k A8[m,k]*B8[n,k] + bias[n];  ss[m] += sum_n C[m,n]^2 (atomic)
//
// Per K-tile kt (single phase, one barrier):
//   ds_read bq(4 b128) + a01(4) + a23(4) from buf[kt%3];
//   stage A(kt+2)(4 gloads) + B(kt+2)(2) into buf[(kt+2)%3];
//   setprio(1); 8 MFMA; setprio(0);
//   vmcnt(6)  [drains exactly tile kt+1; kt+2's 6 loads stay in flight]; s_barrier
//
// Slot-reuse safety: buf[(kt+2)%3] was last ds_read at kt-1; those reads are consumed
// by kt-1's MFMAs (compiler lgkm waits) BEFORE the end-of-(kt-1) barrier, which every
// wave passes before any wave stages at kt.  vmcnt FIFO induction (6 loads per tile):
// after kt's stages the queue is [T(kt+1):6, T(kt+2):6] -> vmcnt(6) == T(kt+1) landed.
__global__ __launch_bounds__(256, 2) void gemm_fp8_kernel(const unsigned char* __restrict__ A,   // [M_SZ,F_SZ] fp8
                                                          const unsigned char* __restrict__ Bt,  // [H_SZ,F_SZ] fp8 (x256)
                                                          const float* __restrict__ bias,        // [H_SZ]
                                                          __hip_bfloat16* __restrict__ C,        // [M_SZ,H_SZ] bf16
                                                          float* __restrict__ ss)                // [M_SZ] atomic SS
{
    __shared__ __align__(16) unsigned char smem[3 * TILE_BYTES];  // 72 KB -> 2 blocks/CU

    const int tid  = threadIdx.x;
    const int lane = tid & 63;
    const int wave = tid >> 6;           // 0..3
    const int wm   = wave >> 1;          // 0..1 -> 128-row half
    const int wn   = wave & 1;           // 0..1 -> 64-col half
    const int l31  = lane & 31;
    const int kh   = lane >> 5;          // k-half within the 64B MFMA slice

    // bijective XCD-chunk swizzle: 1024 blocks, XCD k (= flat%8) gets logical ids
    // [k*128, (k+1)*128) -> 8 m-blocks x all 16 n-blocks; L2-resident working set.
    const int flat = blockIdx.y * 16 + blockIdx.x;
    const int swz  = (flat & 7) * 128 + (flat >> 3);
    const int n0   = (swz & 15) * BN;
    const int m0   = (swz >> 4) * BM;

    const unsigned char* const Ap = A  + (size_t)m0 * F_SZ;
    const unsigned char* const Bp = Bt + (size_t)n0 * F_SZ;

    // staging offsets (row-major 64B rows, 4 x 16B units, phys_u = log_u ^ ((row>>1)&3),
    // applied on the global source; LDS linear)
    int sAg[4], sAl[4];
    #pragma unroll
    for (int j = 0; j < 4; ++j) {
        const int c = j * 256 + tid;
        const int row = c >> 2;
        const int u = (c & 3) ^ ((row >> 1) & 3);
        sAg[j] = row * F_SZ + u * 16;
        sAl[j] = c * 16;
    }
    int sBg[2], sBl[2];
    #pragma unroll
    for (int j = 0; j < 2; ++j) {
        const int c = j * 256 + tid;
        const int row = c >> 2;
        const int u = (c & 3) ^ ((row >> 1) & 3);
        sBg[j] = row * F_SZ + u * 16;
        sBl[j] = c * 16;
    }

    // fragment read offsets (same involution)
    int aoff[4][2], boff[2][2];
    #pragma unroll
    for (int mi = 0; mi < 4; ++mi) {
        const int ra = wm * 128 + mi * 32 + l31;
        #pragma unroll
        for (int j = 0; j < 2; ++j)
            aoff[mi][j] = ra * BK + (((kh * 2 + j) ^ ((ra >> 1) & 3)) * 16);
    }
    #pragma unroll
    for (int ni = 0; ni < 2; ++ni) {
        const int rb = wn * 64 + ni * 32 + l31;
        #pragma unroll
        for (int j = 0; j < 2; ++j)
            boff[ni][j] = rb * BK + (((kh * 2 + j) ^ ((rb >> 1) & 3)) * 16);
    }

    auto stageA = [&](int p, int kt) {
        unsigned char* const d = smem + p * TILE_BYTES;
        #pragma unroll
        for (int j = 0; j < 4; ++j) gload_lds16(Ap + kt * BK + sAg[j], d + sAl[j]);
    };
    auto stageB = [&](int p, int kt) {
        unsigned char* const d = smem + p * TILE_BYTES + ABYTES;
        #pragma unroll
        for (int j = 0; j < 2; ++j) gload_lds16(Bp + kt * BK + sBg[j], d + sBl[j]);
    };

    f32x16 acc[4][2] = {};

    // prologue: tiles 0 and 1 staged.  Queue [T0:6, T1:6] -> vmcnt(6).
    stageA(0, 0); stageB(0, 0);
    stageA(1, 1); stageB(1, 1);
    asm volatile("s_waitcnt vmcnt(6)" ::: "memory");
    sbar();

    int cur = 0;                          // kt % 3
    #pragma unroll 1
    for (int kt = 0; kt < NT; ++kt) {
        unsigned char* const buf = smem + cur * TILE_BYTES;
        unsigned char* const Bs  = buf + ABYTES;

        i32x8 a01[2], a23[2], bq[2];
        #pragma unroll
        for (int ni = 0; ni < 2; ++ni) {
            ((int4*)&bq[ni])[0] = *(const int4*)(Bs + boff[ni][0]);
            ((int4*)&bq[ni])[1] = *(const int4*)(Bs + boff[ni][1]);
        }
        #pragma unroll
        for (int mi = 0; mi < 2; ++mi) {
            ((int4*)&a01[mi])[0] = *(const int4*)(buf + aoff[mi][0]);
            ((int4*)&a01[mi])[1] = *(const int4*)(buf + aoff[mi][1]);
            ((int4*)&a23[mi])[0] = *(const int4*)(buf + aoff[2 + mi][0]);
            ((int4*)&a23[mi])[1] = *(const int4*)(buf + aoff[2 + mi][1]);
        }

        if (kt + 2 < NT) {
            const int p2 = (cur + 2 >= 3) ? cur - 1 : cur + 2;   // (kt+2) % 3
            stageA(p2, kt + 2);
            stageB(p2, kt + 2);
        }

        __builtin_amdgcn_s_setprio(1);
        acc[0][0] = MFMA_FP8(a01[0], bq[0], acc[0][0]);
        acc[0][1] = MFMA_FP8(a01[0], bq[1], acc[0][1]);
        acc[1][0] = MFMA_FP8(a01[1], bq[0], acc[1][0]);
        acc[1][1] = MFMA_FP8(a01[1], bq[1], acc[1][1]);
        acc[2][0] = MFMA_FP8(a23[0], bq[0], acc[2][0]);
        acc[2][1] = MFMA_FP8(a23[0], bq[1], acc[2][1]);
        acc[3][0] = MFMA_FP8(a23[1], bq[0], acc[3][0]);
        acc[3][1] = MFMA_FP8(a23[1], bq[1], acc[3][1]);
        __builtin_amdgcn_s_setprio(0);

        if (kt < NT - 2)       { asm volatile("s_waitcnt vmcnt(6)" ::: "memory"); }
        else if (kt == NT - 2) { asm volatile("s_waitcnt vmcnt(0)" ::: "memory"); }
        if (kt < NT - 1) sbar();

        cur = (cur + 1 >= 3) ? 0 : cur + 1;
    }

    // epilogue: 32x32 C/D layout col=lane&31, row=(r&3)+8*(r>>2)+4*(lane>>5)  (m74/m101-verified)
    float bv[2];
    #pragma unroll
    for (int ni = 0; ni < 2; ++ni) bv[ni] = bias[n0 + wn * 64 + ni * 32 + l31];
    #pragma unroll
    for (int mi = 0; mi < 4; ++mi) {
        const int gmb = m0 + wm * 128 + mi * 32 + 4 * kh;
        #pragma unroll
        for (int r = 0; r < 16; ++r) {
            const int grow = gmb + (r & 3) + 8 * (r >> 2);
            float p = 0.f;
            #pragma unroll
            for (int ni = 0; ni < 2; ++ni) {
                const int gn = n0 + wn * 64 + ni * 32 + l31;
                const float val = acc[mi][ni][r] * (1.0f / 256.0f) + bv[ni];
                C[(size_t)grow * H_SZ + gn] = __float2bfloat16(val);
                p += val * val;
            }
            // cross-lane: sum over the 32 col-lanes (masks<32 stay in-half)
            p += __shfl_xor(p, 1, 64);
            p += __shfl_xor(p, 2, 64);
            p += __shfl_xor(p, 4, 64);
            p += __shfl_xor(p, 8, 64);
            p += __shfl_xor(p, 16, 64);
            if (l31 == 0) atomicAdd(ss + grow, p);
        }
    }
}

// ---------------- LIF scan: 4 columns/thread, inv-norm in LDS, 3-deep load pipeline ----
// (byte-identical to the R4-passing build)
__global__ __launch_bounds__(256) void lif_scan_kernel(const __hip_bfloat16* __restrict__ cur, // [M_SZ,H_SZ]
                                                       const float* __restrict__ ss,           // [M_SZ] sum-of-squares
                                                       float* __restrict__ spk,                // [T,B,H]
                                                       float* __restrict__ cnt)                // [B,H]
{
    __shared__ float s_inv[T_SZ];
    const int gid = blockIdx.x * 256 + threadIdx.x;     // 262144 threads
    const int b   = gid >> 9;                           // uniform within a block
    const int h0  = (gid & 511) * 4;

    if (threadIdx.x < T_SZ)
        s_inv[threadIdx.x] = 1.0f / fmaxf(sqrtf(ss[threadIdx.x * B_SZ + b]), 1e-12f);
    __syncthreads();

    const size_t stride = (size_t)B_SZ * H_SZ;
    const size_t base   = (size_t)b * H_SZ + h0;
    const __hip_bfloat16* p = cur + base;

    ushort4 pk[3];
    pk[0] = *(const ushort4*)(p);
    pk[1] = *(const ushort4*)(p + stride);
    pk[2] = *(const ushort4*)(p + 2 * stride);

    float v[4]  = {0, 0, 0, 0};
    float cn[4] = {0, 0, 0, 0};
    #pragma unroll
    for (int t = 0; t < T_SZ; ++t) {
        const ushort4 k = pk[t % 3];
        if (t + 3 < T_SZ) pk[t % 3] = *(const ushort4*)(p + (size_t)(t + 3) * stride);
        const float inv = s_inv[t];
        float so[4];
        {
            float c;
            c = bf16_bits_to_f32(k.x) * inv; v[0] += (c - v[0]) * 0.5f;
            c = bf16_bits_to_f32(k.y) * inv; v[1] += (c - v[1]) * 0.5f;
            c = bf16_bits_to_f32(k.z) * inv; v[2] += (c - v[2]) * 0.5f;
            c = bf16_bits_to_f32(k.w) * inv; v[3] += (c - v[3]) * 0.5f;
        }
        #pragma unroll
        for (int j = 0; j < 4; ++j) {
            float s = (v[j] >= 1.0f) ? 1.0f : 0.0f;
            so[j] = s;
            cn[j] += s;
            v[j] = (s != 0.f) ? 0.f : v[j];
        }
        *(float4*)(spk + base + (size_t)t * stride) = make_float4(so[0], so[1], so[2], so[3]);
    }
    *(float4*)(cnt + base) = make_float4(cn[0], cn[1], cn[2], cn[3]);
}

extern "C" void kernel_launch(void* const* d_in, const int* in_sizes, int n_in,
                              void* d_out, int out_size, void* d_ws, size_t ws_size,
                              hipStream_t stream) {
    const float* x    = (const float*)d_in[0];   // [T,B,F] fp32
    const float* W    = (const float*)d_in[1];   // [H,F]  fp32
    const float* bias = (const float*)d_in[2];   // [H]    fp32

    float* spk = (float*)d_out;                          // [T,B,H]
    float* cnt = spk + (size_t)T_SZ * B_SZ * H_SZ;       // [B,H]

    char* ws = (char*)d_ws;
    unsigned char* x8    = (unsigned char*)ws;                                   // 33.5 MB
    unsigned char* W8    = x8 + (size_t)M_SZ * F_SZ;                             // 4.2 MB
    __hip_bfloat16* curb = (__hip_bfloat16*)(W8 + (size_t)H_SZ * F_SZ);          // 67.1 MB
    float* ss            = (float*)((char*)curb + (size_t)M_SZ * H_SZ * 2);      // 64 KB

    prep_kernel<<<NBLK_X + NBLK_W + NBLK_S, 256, 0, stream>>>(
        x, W, (unsigned int*)x8, (unsigned int*)W8, (float4*)ss);
    gemm_fp8_kernel<<<dim3(H_SZ / BN, M_SZ / BM), 256, 0, stream>>>(x8, W8, bias, curb, ss);
    lif_scan_kernel<<<(B_SZ * H_SZ / 4) / 256, 256, 0, stream>>>(curb, ss, spk, cnt);
}